// Round 1
// baseline (5194.949 us; speedup 1.0000x reference)
//
#include <hip/hip_runtime.h>
#include <cstdint>

#define N_U 100000
#define N_I 50000
#define DIM 64
#define RANK 5
#define NNZ_ 2000000
#define M_U 2048
#define M_I 4096
#define RPB 16
#define NCHUNK 8

// ---- workspace layout (floats) ----
static constexpr size_t ZU1 = 0;               // 6.4M
static constexpr size_t ZI1 = 6400000;         // 3.2M
static constexpr size_t ZU2 = 9600000;         // 6.4M
static constexpr size_t ZI2 = 16000000;        // 3.2M
static constexpr size_t P_OFF = 19200000;      // 320
static constexpr size_t Q_OFF = 19200320;      // 320
static constexpr size_t ACC_OFF = 19200640;    // 1
static constexpr size_t ZERO_FLOATS = 19200641;// memset range end
static constexpr size_t EU0 = 19200768;        // 6.4M
static constexpr size_t EI0 = EU0 + 6400000;   // 3.2M
static constexpr size_t GSU = EI0 + 3200000;   // 2048*64
static constexpr size_t GSI = GSU + (size_t)M_U*64;      // 4096*64
static constexpr size_t PART_U = GSI + (size_t)M_I*64;   // 2048*8*2
static constexpr size_t PART_I = PART_U + (size_t)M_U*NCHUNK*2; // 4096*8*2

__global__ void ew_add_kernel(const float4* __restrict__ a, const float4* __restrict__ b,
                              float4* __restrict__ o, int n) {
    int i = blockIdx.x * blockDim.x + threadIdx.x;
    if (i < n) {
        float4 x = a[i], y = b[i];
        o[i] = make_float4(x.x + y.x, x.y + y.y, x.z + y.z, x.w + y.w);
    }
}

__global__ void spmm_kernel(const int* __restrict__ rows, const int* __restrict__ cols,
                            const float* __restrict__ vals,
                            const float* __restrict__ Eu, const float* __restrict__ Ei,
                            float* __restrict__ Zu, float* __restrict__ Zi) {
    int lane = threadIdx.x & 63;
    int wave = (blockIdx.x * blockDim.x + threadIdx.x) >> 6;
    int nw = (gridDim.x * blockDim.x) >> 6;
    for (int e = wave; e < NNZ_; e += nw) {
        int r = rows[e], c = cols[e];
        float v = vals[e];
        float a = Eu[r * 64 + lane];
        float b = Ei[c * 64 + lane];
        atomicAdd(&Zu[r * 64 + lane], v * b);
        atomicAdd(&Zi[c * 64 + lane], v * a);
    }
}

__global__ void rank_kernel(const float* __restrict__ X, const float* __restrict__ W,
                            float* __restrict__ P, int n) {
    int lane = threadIdx.x & 63;
    int wave = (blockIdx.x * blockDim.x + threadIdx.x) >> 6;
    int nw = (gridDim.x * blockDim.x) >> 6;
    float acc[RANK] = {0.f, 0.f, 0.f, 0.f, 0.f};
    for (int i = wave; i < n; i += nw) {
        float x = X[i * 64 + lane];
#pragma unroll
        for (int r = 0; r < RANK; r++) acc[r] = __builtin_fmaf(W[r * n + i], x, acc[r]);
    }
#pragma unroll
    for (int r = 0; r < RANK; r++) atomicAdd(&P[r * 64 + lane], acc[r]);
}

__global__ void finalize_kernel(const float4* __restrict__ e0, const float4* __restrict__ z1,
                                const float4* __restrict__ z2, float4* __restrict__ out, int n) {
    int i = blockIdx.x * blockDim.x + threadIdx.x;
    if (i < n) {
        float4 a = e0[i], b = z1[i], c = z2[i];
        const float s = 1.f / 3.f;
        out[i] = make_float4((a.x + b.x + c.x) * s, (a.y + b.y + c.y) * s,
                             (a.z + b.z + c.z) * s, (a.w + b.w + c.w) * s);
    }
}

__global__ void gather_kernel(const int* __restrict__ ids, int m,
                              const float* __restrict__ E0, const float* __restrict__ PQ,
                              const float* __restrict__ mulS, const float* __restrict__ Eout,
                              float* __restrict__ Gs, float* __restrict__ acc, float coef) {
    int lane = threadIdx.x & 63;
    int k = (blockIdx.x * blockDim.x + threadIdx.x) >> 6;
    if (k >= m) return;
    int u = ids[k];
    float g = E0[u * 64 + lane];
#pragma unroll
    for (int r = 0; r < RANK; r++) g = __builtin_fmaf(mulS[u * RANK + r], PQ[r * 64 + lane], g);
    g *= (1.f / 3.f);
    Gs[k * 64 + lane] = g;
    float d = g * Eout[u * 64 + lane];
#pragma unroll
    for (int off = 32; off; off >>= 1) d += __shfl_down(d, off);
    if (lane == 0) {
        float t = fminf(fmaxf(d * 5.f, -5.f), 5.f);
        atomicAdd(acc, coef * t);
    }
}

__global__ __launch_bounds__(256) void neg_kernel(const float* __restrict__ Gs,
                                                  const float* __restrict__ E,
                                                  float* __restrict__ part, int n) {
    // 16 G-rows per block; their values are wave-uniform -> scalar loads.
    const float* g = Gs + (size_t)blockIdx.y * RPB * 64;
    int per = n / NCHUNK;
    int c0 = blockIdx.x * per;
    float m[RPB], s[RPB], a[RPB];
#pragma unroll
    for (int r = 0; r < RPB; r++) { m[r] = -1e30f; s[r] = 0.f; }
    for (int j = c0 + threadIdx.x; j < c0 + per; j += 256) {
        const float4* e = (const float4*)(E + (size_t)j * 64);
#pragma unroll
        for (int r = 0; r < RPB; r++) a[r] = 0.f;
#pragma unroll
        for (int kk = 0; kk < 16; kk++) {
            float4 ev = e[kk];
#pragma unroll
            for (int r = 0; r < RPB; r++) {
                a[r] = __builtin_fmaf(g[r * 64 + kk * 4 + 0], ev.x, a[r]);
                a[r] = __builtin_fmaf(g[r * 64 + kk * 4 + 1], ev.y, a[r]);
                a[r] = __builtin_fmaf(g[r * 64 + kk * 4 + 2], ev.z, a[r]);
                a[r] = __builtin_fmaf(g[r * 64 + kk * 4 + 3], ev.w, a[r]);
            }
        }
#pragma unroll
        for (int r = 0; r < RPB; r++) {
            float l = a[r] * 5.f;  // /TEMP
            float M = fmaxf(m[r], l);
            s[r] = s[r] * __expf(m[r] - M) + __expf(l - M);
            m[r] = M;
        }
    }
    // wave-level online-softmax reduce
    int lane = threadIdx.x & 63, w = threadIdx.x >> 6;
#pragma unroll
    for (int r = 0; r < RPB; r++) {
#pragma unroll
        for (int off = 32; off; off >>= 1) {
            float mo = __shfl_down(m[r], off), so = __shfl_down(s[r], off);
            float M = fmaxf(m[r], mo);
            s[r] = s[r] * __expf(m[r] - M) + so * __expf(mo - M);
            m[r] = M;
        }
    }
    __shared__ float redm[RPB][4], reds[RPB][4];
    if (lane == 0) {
#pragma unroll
        for (int r = 0; r < RPB; r++) { redm[r][w] = m[r]; reds[r][w] = s[r]; }
    }
    __syncthreads();
    if (threadIdx.x < RPB) {
        int r = threadIdx.x;
        float M = redm[r][0], S = reds[r][0];
#pragma unroll
        for (int w2 = 1; w2 < 4; w2++) {
            float mo = redm[r][w2], so = reds[r][w2];
            float M2 = fmaxf(M, mo);
            S = S * __expf(M - M2) + so * __expf(mo - M2);
            M = M2;
        }
        int row = blockIdx.y * RPB + r;
        part[(row * NCHUNK + blockIdx.x) * 2 + 0] = M;
        part[(row * NCHUNK + blockIdx.x) * 2 + 1] = S;
    }
}

__global__ void combine_kernel(const float* __restrict__ part, int m,
                               float* __restrict__ acc, float coef) {
    int row = blockIdx.x * blockDim.x + threadIdx.x;
    if (row >= m) return;
    float M = -1e30f, S = 0.f;
#pragma unroll
    for (int c = 0; c < NCHUNK; c++) {
        float mo = part[(row * NCHUNK + c) * 2 + 0];
        float so = part[(row * NCHUNK + c) * 2 + 1];
        float M2 = fmaxf(M, mo);
        S = S * __expf(M - M2) + so * __expf(mo - M2);
        M = M2;
    }
    float lse = M + __logf(S);
    atomicAdd(acc, coef * lse);
}

__global__ void cat_kernel(const float* __restrict__ img, const float* __restrict__ txt,
                           float* __restrict__ out, int nrows) {
    int lane = threadIdx.x & 63;
    int row = (blockIdx.x * blockDim.x + threadIdx.x) >> 6;
    if (row >= nrows) return;
    float a = img[row * 64 + lane], b = txt[row * 64 + lane];
    float sa = a * a, sb = b * b;
#pragma unroll
    for (int msk = 32; msk; msk >>= 1) { sa += __shfl_xor(sa, msk); sb += __shfl_xor(sb, msk); }
    float ia = 1.f / fmaxf(sqrtf(sa), 1e-12f);
    float ib = 1.f / fmaxf(sqrtf(sb), 1e-12f);
    out[row * 64 + lane] += 0.02f * (a * ia + b * ib);
}

__global__ void loss_write_kernel(const float* __restrict__ acc, float* __restrict__ out) {
    out[0] = acc[0];
}

extern "C" void kernel_launch(void* const* d_in, const int* in_sizes, int n_in,
                              void* d_out, int out_size, void* d_ws, size_t ws_size,
                              hipStream_t stream) {
    const float* user_emb = (const float*)d_in[0];
    const float* item_emb = (const float*)d_in[1];
    const float* user_pre = (const float*)d_in[2];
    const float* item_pre = (const float*)d_in[3];
    const float* img_i = (const float*)d_in[4];
    const float* txt_i = (const float*)d_in[5];
    const float* img_u = (const float*)d_in[6];
    const float* txt_u = (const float*)d_in[7];
    const int* rows = (const int*)d_in[8];
    const int* cols = (const int*)d_in[9];
    const float* vals = (const float*)d_in[10];
    const float* ut = (const float*)d_in[11];
    const float* vt = (const float*)d_in[12];
    const float* u_mul_s = (const float*)d_in[13];
    const float* v_mul_s = (const float*)d_in[14];
    const int* uids = (const int*)d_in[15];
    const int* iids = (const int*)d_in[16];

    float* ws = (float*)d_ws;
    float* zu1 = ws + ZU1;
    float* zi1 = ws + ZI1;
    float* zu2 = ws + ZU2;
    float* zi2 = ws + ZI2;
    float* P = ws + P_OFF;
    float* Q = ws + Q_OFF;
    float* acc = ws + ACC_OFF;
    float* eu0 = ws + EU0;
    float* ei0 = ws + EI0;
    float* gsu = ws + GSU;
    float* gsi = ws + GSI;
    float* part_u = ws + PART_U;
    float* part_i = ws + PART_I;

    float* out_u = (float*)d_out;
    float* out_i = out_u + (size_t)N_U * 64;
    float* out_loss = out_u + (size_t)(N_U + N_I) * 64;

    // zero accumulators (Zu1,Zi1,Zu2,Zi2,P,Q,acc)
    hipMemsetAsync(ws, 0, ZERO_FLOATS * sizeof(float), stream);

    // E0 = pre + emb
    ew_add_kernel<<<6250, 256, 0, stream>>>((const float4*)user_emb, (const float4*)user_pre,
                                            (float4*)eu0, 1600000);
    ew_add_kernel<<<3125, 256, 0, stream>>>((const float4*)item_emb, (const float4*)item_pre,
                                            (float4*)ei0, 800000);
    // layer-1 rank reductions: P += vt@Ei0, Q += ut@Eu0
    rank_kernel<<<256, 256, 0, stream>>>(ei0, vt, P, N_I);
    rank_kernel<<<256, 256, 0, stream>>>(eu0, ut, Q, N_U);
    // layer-1 SpMM
    spmm_kernel<<<8192, 256, 0, stream>>>(rows, cols, vals, eu0, ei0, zu1, zi1);
    // layer-2 rank reductions: P += vt@Zi1, Q += ut@Zu1
    rank_kernel<<<256, 256, 0, stream>>>(zi1, vt, P, N_I);
    rank_kernel<<<256, 256, 0, stream>>>(zu1, ut, Q, N_U);
    // layer-2 SpMM
    spmm_kernel<<<8192, 256, 0, stream>>>(rows, cols, vals, zu1, zi1, zu2, zi2);
    // E_u/E_i -> d_out (cat terms added later, after loss reads these)
    finalize_kernel<<<6250, 256, 0, stream>>>((const float4*)eu0, (const float4*)zu1,
                                              (const float4*)zu2, (float4*)out_u, 1600000);
    finalize_kernel<<<3125, 256, 0, stream>>>((const float4*)ei0, (const float4*)zi1,
                                              (const float4*)zi2, (float4*)out_i, 800000);
    // sampled G rows + pos term
    gather_kernel<<<M_U / 4, 256, 0, stream>>>(uids, M_U, eu0, P, u_mul_s, out_u, gsu, acc,
                                               -4.f / M_U);
    gather_kernel<<<M_I / 4, 256, 0, stream>>>(iids, M_I, ei0, Q, v_mul_s, out_i, gsi, acc,
                                               -4.f / M_I);
    // neg term: logsumexp over full score rows
    dim3 gu(NCHUNK, M_U / RPB);
    neg_kernel<<<gu, 256, 0, stream>>>(gsu, out_u, part_u, N_U);
    dim3 gi(NCHUNK, M_I / RPB);
    neg_kernel<<<gi, 256, 0, stream>>>(gsi, out_i, part_i, N_I);
    combine_kernel<<<(M_U + 255) / 256, 256, 0, stream>>>(part_u, M_U, acc, 4.f / M_U);
    combine_kernel<<<(M_I + 255) / 256, 256, 0, stream>>>(part_i, M_I, acc, 4.f / M_I);
    // cat-rate terms (after loss consumed E from d_out)
    cat_kernel<<<(N_U * 64 + 255) / 256, 256, 0, stream>>>(img_u, txt_u, out_u, N_U);
    cat_kernel<<<(N_I * 64 + 255) / 256, 256, 0, stream>>>(img_i, txt_i, out_i, N_I);
    loss_write_kernel<<<1, 1, 0, stream>>>(acc, out_loss);
}

// Round 2
// 2565.376 us; speedup vs baseline: 2.0250x; 2.0250x over previous
//
#include <hip/hip_runtime.h>
#include <cstdint>

#define N_U 100000
#define N_I 50000
#define DIM 64
#define RANK 5
#define NNZ_ 2000000
#define M_U 2048
#define M_I 4096

// neg-GEMM tiling
#define CPC 3136            // cols per chunk (196 tiles of 16)
#define NCH_U 32            // chunks for user side  -> Npad_U = 100352
#define NCH_I 16            // chunks for item side  -> Npad_I = 50176
#define NPAD_U (CPC * NCH_U)
#define NPAD_I (CPC * NCH_I)

typedef __attribute__((ext_vector_type(8))) short short8;
typedef __attribute__((ext_vector_type(4))) float floatx4;

// ---- workspace layout (float offsets) ----
static constexpr size_t ZU1 = 0;                 // 6.4M
static constexpr size_t ZI1 = 6400000;           // 3.2M
static constexpr size_t ZU2 = 9600000;           // 6.4M
static constexpr size_t ZI2 = 16000000;          // 3.2M
static constexpr size_t P_OFF = 19200000;        // 320
static constexpr size_t Q_OFF = 19200320;        // 320
static constexpr size_t ACC_OFF = 19200640;      // 1
static constexpr size_t ZERO_FLOATS = 19200641;  // memset range end
static constexpr size_t EU0 = 19200768;          // 6.4M
static constexpr size_t EI0 = EU0 + 6400000;     // 3.2M
static constexpr size_t PART_U = EI0 + 3200000;  // 2048*32 = 65536
static constexpr size_t PART_I = PART_U + (size_t)M_U * NCH_U;  // 4096*16 = 65536
// ---- bf16 overlay: lives inside ZU2 region, valid only AFTER finalize ----
static constexpr size_t EBU16 = ZU2;                   // 100352*64 bf16 = 3,211,264 fl
static constexpr size_t EBI16 = EBU16 + 3211264;       // 50176*64 bf16 = 1,605,632 fl
static constexpr size_t GBU16 = EBI16 + 1605632;       // 2048*64 bf16
static constexpr size_t GBI16 = GBU16 + 65536;         // 4096*64 bf16
// end = 14,613,504 < 16,000,000 (ZI2) -> never touches ZI2

static __device__ __forceinline__ short f2bf(float x) {
    unsigned u = __builtin_bit_cast(unsigned, x);
    unsigned r = (u + 0x7fffu + ((u >> 16) & 1u)) >> 16;
    return (short)r;
}

__global__ void ew_add_kernel(const float4* __restrict__ a, const float4* __restrict__ b,
                              float4* __restrict__ o, int n) {
    int i = blockIdx.x * blockDim.x + threadIdx.x;
    if (i < n) {
        float4 x = a[i], y = b[i];
        o[i] = make_float4(x.x + y.x, x.y + y.y, x.z + y.z, x.w + y.w);
    }
}

__global__ void spmm_kernel(const int* __restrict__ rows, const int* __restrict__ cols,
                            const float* __restrict__ vals,
                            const float* __restrict__ Eu, const float* __restrict__ Ei,
                            float* __restrict__ Zu, float* __restrict__ Zi) {
    int lane = threadIdx.x & 63;
    int wave = (blockIdx.x * blockDim.x + threadIdx.x) >> 6;
    int nw = (gridDim.x * blockDim.x) >> 6;
    for (int e = wave; e < NNZ_; e += nw) {
        int r = rows[e], c = cols[e];
        float v = vals[e];
        float a = Eu[r * 64 + lane];
        float b = Ei[c * 64 + lane];
        atomicAdd(&Zu[r * 64 + lane], v * b);
        atomicAdd(&Zi[c * 64 + lane], v * a);
    }
}

__global__ void rank_kernel(const float* __restrict__ X, const float* __restrict__ W,
                            float* __restrict__ P, int n) {
    int lane = threadIdx.x & 63;
    int wave = (blockIdx.x * blockDim.x + threadIdx.x) >> 6;
    int nw = (gridDim.x * blockDim.x) >> 6;
    float acc[RANK] = {0.f, 0.f, 0.f, 0.f, 0.f};
    for (int i = wave; i < n; i += nw) {
        float x = X[i * 64 + lane];
#pragma unroll
        for (int r = 0; r < RANK; r++) acc[r] = __builtin_fmaf(W[r * n + i], x, acc[r]);
    }
#pragma unroll
    for (int r = 0; r < RANK; r++) atomicAdd(&P[r * 64 + lane], acc[r]);
}

__global__ void finalize_kernel(const float4* __restrict__ e0, const float4* __restrict__ z1,
                                const float4* __restrict__ z2, float4* __restrict__ out, int n) {
    int i = blockIdx.x * blockDim.x + threadIdx.x;
    if (i < n) {
        float4 a = e0[i], b = z1[i], c = z2[i];
        const float s = 1.f / 3.f;
        out[i] = make_float4((a.x + b.x + c.x) * s, (a.y + b.y + c.y) * s,
                             (a.z + b.z + c.z) * s, (a.w + b.w + c.w) * s);
    }
}

// fp32 E -> bf16 E with zero padding rows [n, npad)
__global__ void conv_bf16_kernel(const float* __restrict__ E, short* __restrict__ B,
                                 int n64, int npad64) {
    int i = blockIdx.x * blockDim.x + threadIdx.x;
    if (i < npad64) B[i] = (i < n64) ? f2bf(E[i]) : (short)0;
}

__global__ void gather_kernel(const int* __restrict__ ids, int m,
                              const float* __restrict__ E0, const float* __restrict__ PQ,
                              const float* __restrict__ mulS, const float* __restrict__ Eout,
                              short* __restrict__ Gb, float* __restrict__ acc, float coef) {
    int lane = threadIdx.x & 63;
    int k = (blockIdx.x * blockDim.x + threadIdx.x) >> 6;
    if (k >= m) return;
    int u = ids[k];
    float g = E0[u * 64 + lane];
#pragma unroll
    for (int r = 0; r < RANK; r++) g = __builtin_fmaf(mulS[u * RANK + r], PQ[r * 64 + lane], g);
    g *= (1.f / 3.f);
    Gb[k * 64 + lane] = f2bf(g);
    float d = g * Eout[u * 64 + lane];
#pragma unroll
    for (int off = 32; off; off >>= 1) d += __shfl_down(d, off);
    if (lane == 0) {
        float t = fminf(fmaxf(d * 5.f, -5.f), 5.f);
        atomicAdd(acc, coef * t);
    }
}

// MFMA exp-sum GEMM: block = 4 waves x 16 rows = 64 G-rows, col chunk = CPC.
// grid.x = row tiles (consecutive blocks share a col chunk -> L2 reuse of E),
// grid.y = col chunk.
__global__ __launch_bounds__(256) void neg_mfma_kernel(const short* __restrict__ G16,
                                                       const short* __restrict__ E16,
                                                       float* __restrict__ part, int nchunk) {
    int lane = threadIdx.x & 63;
    int wave = threadIdx.x >> 6;
    int quad = lane >> 4;
    int rr = lane & 15;
    int rowbase = blockIdx.x * 64 + wave * 16;
    const short8* ga = (const short8*)(G16 + (size_t)(rowbase + rr) * 64 + quad * 8);
    short8 a0 = ga[0];  // k in [quad*8, quad*8+8)
    short8 a1 = ga[4];  // k + 32
    int c0 = blockIdx.y * CPC;
    float s0 = 0.f, s1 = 0.f, s2 = 0.f, s3 = 0.f;
    for (int ct = 0; ct < CPC; ct += 16) {
        const short8* eb = (const short8*)(E16 + (size_t)(c0 + ct + rr) * 64 + quad * 8);
        short8 b0 = eb[0];
        short8 b1 = eb[4];
        floatx4 acc = {0.f, 0.f, 0.f, 0.f};
        acc = __builtin_amdgcn_mfma_f32_16x16x32_bf16(a0, b0, acc, 0, 0, 0);
        acc = __builtin_amdgcn_mfma_f32_16x16x32_bf16(a1, b1, acc, 0, 0, 0);
        s0 += __expf(acc[0] * 5.f);
        s1 += __expf(acc[1] * 5.f);
        s2 += __expf(acc[2] * 5.f);
        s3 += __expf(acc[3] * 5.f);
    }
#pragma unroll
    for (int m = 8; m; m >>= 1) {
        s0 += __shfl_xor(s0, m);
        s1 += __shfl_xor(s1, m);
        s2 += __shfl_xor(s2, m);
        s3 += __shfl_xor(s3, m);
    }
    if (rr == 0) {
        int row = rowbase + quad * 4;
        float* p = part + (size_t)row * nchunk + blockIdx.y;
        p[0] = s0;
        p[(size_t)nchunk] = s1;
        p[(size_t)2 * nchunk] = s2;
        p[(size_t)3 * nchunk] = s3;
    }
}

__global__ void combine_kernel(const float* __restrict__ part, int m, int nchunk, float pad,
                               float* __restrict__ acc, float coef) {
    int row = blockIdx.x * blockDim.x + threadIdx.x;
    if (row >= m) return;
    float S = 0.f;
    for (int c = 0; c < nchunk; c++) S += part[row * nchunk + c];
    float lse = __logf(S - pad);
    atomicAdd(acc, coef * lse);
}

__global__ void cat_kernel(const float* __restrict__ img, const float* __restrict__ txt,
                           float* __restrict__ out, int nrows) {
    int lane = threadIdx.x & 63;
    int row = (blockIdx.x * blockDim.x + threadIdx.x) >> 6;
    if (row >= nrows) return;
    float a = img[row * 64 + lane], b = txt[row * 64 + lane];
    float sa = a * a, sb = b * b;
#pragma unroll
    for (int msk = 32; msk; msk >>= 1) { sa += __shfl_xor(sa, msk); sb += __shfl_xor(sb, msk); }
    float ia = 1.f / fmaxf(sqrtf(sa), 1e-12f);
    float ib = 1.f / fmaxf(sqrtf(sb), 1e-12f);
    out[row * 64 + lane] += 0.02f * (a * ia + b * ib);
}

__global__ void loss_write_kernel(const float* __restrict__ acc, float* __restrict__ out) {
    out[0] = acc[0];
}

extern "C" void kernel_launch(void* const* d_in, const int* in_sizes, int n_in,
                              void* d_out, int out_size, void* d_ws, size_t ws_size,
                              hipStream_t stream) {
    const float* user_emb = (const float*)d_in[0];
    const float* item_emb = (const float*)d_in[1];
    const float* user_pre = (const float*)d_in[2];
    const float* item_pre = (const float*)d_in[3];
    const float* img_i = (const float*)d_in[4];
    const float* txt_i = (const float*)d_in[5];
    const float* img_u = (const float*)d_in[6];
    const float* txt_u = (const float*)d_in[7];
    const int* rows = (const int*)d_in[8];
    const int* cols = (const int*)d_in[9];
    const float* vals = (const float*)d_in[10];
    const float* ut = (const float*)d_in[11];
    const float* vt = (const float*)d_in[12];
    const float* u_mul_s = (const float*)d_in[13];
    const float* v_mul_s = (const float*)d_in[14];
    const int* uids = (const int*)d_in[15];
    const int* iids = (const int*)d_in[16];

    float* ws = (float*)d_ws;
    float* zu1 = ws + ZU1;
    float* zi1 = ws + ZI1;
    float* zu2 = ws + ZU2;
    float* zi2 = ws + ZI2;
    float* P = ws + P_OFF;
    float* Q = ws + Q_OFF;
    float* acc = ws + ACC_OFF;
    float* eu0 = ws + EU0;
    float* ei0 = ws + EI0;
    float* part_u = ws + PART_U;
    float* part_i = ws + PART_I;
    short* ebu16 = (short*)(ws + EBU16);
    short* ebi16 = (short*)(ws + EBI16);
    short* gbu16 = (short*)(ws + GBU16);
    short* gbi16 = (short*)(ws + GBI16);

    float* out_u = (float*)d_out;
    float* out_i = out_u + (size_t)N_U * 64;
    float* out_loss = out_u + (size_t)(N_U + N_I) * 64;

    // zero accumulators (Zu1,Zi1,Zu2,Zi2,P,Q,acc)
    hipMemsetAsync(ws, 0, ZERO_FLOATS * sizeof(float), stream);

    // E0 = pre + emb
    ew_add_kernel<<<6250, 256, 0, stream>>>((const float4*)user_emb, (const float4*)user_pre,
                                            (float4*)eu0, 1600000);
    ew_add_kernel<<<3125, 256, 0, stream>>>((const float4*)item_emb, (const float4*)item_pre,
                                            (float4*)ei0, 800000);
    // layer-1 rank reductions
    rank_kernel<<<256, 256, 0, stream>>>(ei0, vt, P, N_I);
    rank_kernel<<<256, 256, 0, stream>>>(eu0, ut, Q, N_U);
    // layer-1 SpMM
    spmm_kernel<<<8192, 256, 0, stream>>>(rows, cols, vals, eu0, ei0, zu1, zi1);
    // layer-2 rank reductions
    rank_kernel<<<256, 256, 0, stream>>>(zi1, vt, P, N_I);
    rank_kernel<<<256, 256, 0, stream>>>(zu1, ut, Q, N_U);
    // layer-2 SpMM
    spmm_kernel<<<8192, 256, 0, stream>>>(rows, cols, vals, zu1, zi1, zu2, zi2);
    // E_u/E_i -> d_out
    finalize_kernel<<<6250, 256, 0, stream>>>((const float4*)eu0, (const float4*)zu1,
                                              (const float4*)zu2, (float4*)out_u, 1600000);
    finalize_kernel<<<3125, 256, 0, stream>>>((const float4*)ei0, (const float4*)zi1,
                                              (const float4*)zi2, (float4*)out_i, 800000);
    // bf16 copies of E (overwrites dead ZU2 region; zero-padded tail rows)
    conv_bf16_kernel<<<(NPAD_U * 64 + 255) / 256, 256, 0, stream>>>(out_u, ebu16, N_U * 64,
                                                                   NPAD_U * 64);
    conv_bf16_kernel<<<(NPAD_I * 64 + 255) / 256, 256, 0, stream>>>(out_i, ebi16, N_I * 64,
                                                                   NPAD_I * 64);
    // sampled G rows (bf16) + pos term (fp32)
    gather_kernel<<<M_U / 4, 256, 0, stream>>>(uids, M_U, eu0, P, u_mul_s, out_u, gbu16, acc,
                                               -4.f / M_U);
    gather_kernel<<<M_I / 4, 256, 0, stream>>>(iids, M_I, ei0, Q, v_mul_s, out_i, gbi16, acc,
                                               -4.f / M_I);
    // neg term: MFMA exp-sum
    dim3 gu(M_U / 64, NCH_U);
    neg_mfma_kernel<<<gu, 256, 0, stream>>>(gbu16, ebu16, part_u, NCH_U);
    dim3 gi(M_I / 64, NCH_I);
    neg_mfma_kernel<<<gi, 256, 0, stream>>>(gbi16, ebi16, part_i, NCH_I);
    combine_kernel<<<(M_U + 255) / 256, 256, 0, stream>>>(part_u, M_U, NCH_U,
                                                          (float)(NPAD_U - N_U), acc, 4.f / M_U);
    combine_kernel<<<(M_I + 255) / 256, 256, 0, stream>>>(part_i, M_I, NCH_I,
                                                          (float)(NPAD_I - N_I), acc, 4.f / M_I);
    // cat-rate terms (after loss consumed E from d_out)
    cat_kernel<<<(N_U * 64 + 255) / 256, 256, 0, stream>>>(img_u, txt_u, out_u, N_U);
    cat_kernel<<<(N_I * 64 + 255) / 256, 256, 0, stream>>>(img_i, txt_i, out_i, N_I);
    loss_write_kernel<<<1, 1, 0, stream>>>(acc, out_loss);
}

// Round 3
// 1728.703 us; speedup vs baseline: 3.0051x; 1.4840x over previous
//
#include <hip/hip_runtime.h>
#include <cstdint>

#define N_U 100000
#define N_I 50000
#define DIM 64
#define RANK 5
#define NNZ_ 2000000
#define M_U 2048
#define M_I 4096
#define NSEG 150000  // N_U + N_I combined segment count

// neg-GEMM tiling
#define CPC 3136
#define NCH_U 32
#define NCH_I 16
#define NPAD_U (CPC * NCH_U)
#define NPAD_I (CPC * NCH_I)

typedef __attribute__((ext_vector_type(8))) short short8;
typedef __attribute__((ext_vector_type(4))) float floatx4;

// ---- workspace layout (float offsets) ----
static constexpr size_t ZU1 = 0;                       // 6.4M
static constexpr size_t ZI1 = 6400000;                 // 3.2M
static constexpr size_t EDGE = 9600000;                // 4M entries x 8B = 8M floats
static constexpr size_t P_OFF = 17600000;              // 320
static constexpr size_t Q_OFF = 17600320;              // 320
static constexpr size_t ACC_OFF = 17600640;            // 1 (pad to 704)
static constexpr size_t CNT_OFF = 17600704;            // 150000 ints
static constexpr size_t ZERO_END = 17750704;           // memset [P_OFF, ZERO_END)
static constexpr size_t OFF_OFF = 17750704;            // 150016 ints
static constexpr size_t BSUM_OFF = 17900720;           // 1024 ints
static constexpr size_t EU0 = 17901824;                // 6.4M
static constexpr size_t EI0 = EU0 + 6400000;           // 3.2M
static constexpr size_t PART_U = EI0 + 3200000;        // 2048*32
static constexpr size_t PART_I = PART_U + (size_t)M_U * NCH_U;  // 4096*16
// total = 27,632,896 floats = 110.5 MB (< 115.7 MB proven in R1)
// ---- bf16 overlay inside ZU1 (zu1/zi1 dead after layer-2 spmm) ----
static constexpr size_t EBU16 = 0;                     // 3,211,264 fl
static constexpr size_t EBI16 = 3211264;               // 1,605,632 fl
static constexpr size_t GBU16 = EBI16 + 1605632;       // 65,536 fl
static constexpr size_t GBI16 = GBU16 + 65536;         // 131,072 fl -> end 5,013,504 < 6.4M

static __device__ __forceinline__ short f2bf(float x) {
    unsigned u = __builtin_bit_cast(unsigned, x);
    unsigned r = (u + 0x7fffu + ((u >> 16) & 1u)) >> 16;
    return (short)r;
}

__global__ void ew_add_kernel(const float4* __restrict__ a, const float4* __restrict__ b,
                              float4* __restrict__ o, int n) {
    int i = blockIdx.x * blockDim.x + threadIdx.x;
    if (i < n) {
        float4 x = a[i], y = b[i];
        o[i] = make_float4(x.x + y.x, x.y + y.y, x.z + y.z, x.w + y.w);
    }
}

// ---------- CSR/CSC build ----------
__global__ void hist_kernel(const int* __restrict__ rows, const int* __restrict__ cols,
                            int* __restrict__ cnt) {
    int e = blockIdx.x * blockDim.x + threadIdx.x;
    if (e >= NNZ_) return;
    atomicAdd(&cnt[rows[e]], 1);
    atomicAdd(&cnt[N_U + cols[e]], 1);
}

__global__ void scan1_kernel(const int* __restrict__ cnt, int* __restrict__ bsum, int n) {
    int i = blockIdx.x * 256 + threadIdx.x;
    int v = (i < n) ? cnt[i] : 0;
#pragma unroll
    for (int off = 32; off; off >>= 1) v += __shfl_down(v, off);
    __shared__ int ls[4];
    int lane = threadIdx.x & 63, w = threadIdx.x >> 6;
    if (lane == 0) ls[w] = v;
    __syncthreads();
    if (threadIdx.x == 0) bsum[blockIdx.x] = ls[0] + ls[1] + ls[2] + ls[3];
}

__global__ void scan2_kernel(int* __restrict__ bsum, int nb) {
    __shared__ int s[1024];
    int t = threadIdx.x;
    s[t] = (t < nb) ? bsum[t] : 0;
    __syncthreads();
    for (int off = 1; off < 1024; off <<= 1) {
        int v = (t >= off) ? s[t - off] : 0;
        __syncthreads();
        s[t] += v;
        __syncthreads();
    }
    if (t < nb) bsum[t] = (t == 0) ? 0 : s[t - 1];
}

__global__ void scan3_kernel(const int* __restrict__ cnt, const int* __restrict__ bsum,
                             int* __restrict__ off, int n) {
    __shared__ int s[256];
    int i = blockIdx.x * 256 + threadIdx.x;
    int t = threadIdx.x;
    int c = (i < n) ? cnt[i] : 0;
    s[t] = c;
    __syncthreads();
    for (int o = 1; o < 256; o <<= 1) {
        int v = (t >= o) ? s[t - o] : 0;
        __syncthreads();
        s[t] += v;
        __syncthreads();
    }
    if (i < n) off[i] = bsum[blockIdx.x] + s[t] - c;
}

__global__ void scatter_kernel(const int* __restrict__ rows, const int* __restrict__ cols,
                               const float* __restrict__ vals, int* __restrict__ off,
                               float2* __restrict__ edge) {
    int e = blockIdx.x * blockDim.x + threadIdx.x;
    if (e >= NNZ_) return;
    int r = rows[e], c = cols[e];
    float v = vals[e];
    int pU = atomicAdd(&off[r], 1);
    edge[pU] = make_float2(__int_as_float(c), v);
    int pI = atomicAdd(&off[N_U + c], 1);
    edge[pI] = make_float2(__int_as_float(r), v);
}

// wave-per-row CSR SpMM; off[] holds END offsets (post-scatter), range = [end-cnt, end)
__global__ __launch_bounds__(256) void spmm_csr_kernel(
    const float2* __restrict__ edge, const int* __restrict__ off, const int* __restrict__ cnt,
    int base, const float* __restrict__ Esrc, float* __restrict__ out, float scale, int accum,
    int nrows) {
    int lane = threadIdx.x & 63;
    int row = (blockIdx.x * blockDim.x + threadIdx.x) >> 6;
    if (row >= nrows) return;
    int end = off[base + row];
    int n = cnt[base + row];
    int e = end - n;
    float acc = 0.f;
    for (; e + 4 <= end; e += 4) {
        float2 p0 = edge[e], p1 = edge[e + 1], p2 = edge[e + 2], p3 = edge[e + 3];
        float g0 = Esrc[(size_t)__float_as_int(p0.x) * 64 + lane];
        float g1 = Esrc[(size_t)__float_as_int(p1.x) * 64 + lane];
        float g2 = Esrc[(size_t)__float_as_int(p2.x) * 64 + lane];
        float g3 = Esrc[(size_t)__float_as_int(p3.x) * 64 + lane];
        acc = __builtin_fmaf(p0.y, g0, acc);
        acc = __builtin_fmaf(p1.y, g1, acc);
        acc = __builtin_fmaf(p2.y, g2, acc);
        acc = __builtin_fmaf(p3.y, g3, acc);
    }
    for (; e < end; e++) {
        float2 p = edge[e];
        acc = __builtin_fmaf(p.y, Esrc[(size_t)__float_as_int(p.x) * 64 + lane], acc);
    }
    size_t o = (size_t)row * 64 + lane;
    if (accum) out[o] += scale * acc;
    else out[o] = acc;
}

__global__ void rank_kernel(const float* __restrict__ X, const float* __restrict__ W,
                            float* __restrict__ P, int n) {
    int lane = threadIdx.x & 63;
    int wave = (blockIdx.x * blockDim.x + threadIdx.x) >> 6;
    int nw = (gridDim.x * blockDim.x) >> 6;
    float acc[RANK] = {0.f, 0.f, 0.f, 0.f, 0.f};
    for (int i = wave; i < n; i += nw) {
        float x = X[i * 64 + lane];
#pragma unroll
        for (int r = 0; r < RANK; r++) acc[r] = __builtin_fmaf(W[r * n + i], x, acc[r]);
    }
#pragma unroll
    for (int r = 0; r < RANK; r++) atomicAdd(&P[r * 64 + lane], acc[r]);
}

// out = (a + b) / 3   (layer-2 spmm then adds its term in accumulate mode)
__global__ void pre_out_kernel(const float4* __restrict__ a, const float4* __restrict__ b,
                               float4* __restrict__ o, int n) {
    int i = blockIdx.x * blockDim.x + threadIdx.x;
    if (i < n) {
        float4 x = a[i], y = b[i];
        const float s = 1.f / 3.f;
        o[i] = make_float4((x.x + y.x) * s, (x.y + y.y) * s, (x.z + y.z) * s, (x.w + y.w) * s);
    }
}

__global__ void conv_bf16_kernel(const float* __restrict__ E, short* __restrict__ B, int n64,
                                 int npad64) {
    int i = blockIdx.x * blockDim.x + threadIdx.x;
    if (i < npad64) B[i] = (i < n64) ? f2bf(E[i]) : (short)0;
}

__global__ void gather_kernel(const int* __restrict__ ids, int m, const float* __restrict__ E0,
                              const float* __restrict__ PQ, const float* __restrict__ mulS,
                              const float* __restrict__ Eout, short* __restrict__ Gb,
                              float* __restrict__ acc, float coef) {
    int lane = threadIdx.x & 63;
    int k = (blockIdx.x * blockDim.x + threadIdx.x) >> 6;
    if (k >= m) return;
    int u = ids[k];
    float g = E0[u * 64 + lane];
#pragma unroll
    for (int r = 0; r < RANK; r++) g = __builtin_fmaf(mulS[u * RANK + r], PQ[r * 64 + lane], g);
    g *= (1.f / 3.f);
    Gb[k * 64 + lane] = f2bf(g);
    float d = g * Eout[u * 64 + lane];
#pragma unroll
    for (int off = 32; off; off >>= 1) d += __shfl_down(d, off);
    if (lane == 0) {
        float t = fminf(fmaxf(d * 5.f, -5.f), 5.f);
        atomicAdd(acc, coef * t);
    }
}

__global__ __launch_bounds__(256) void neg_mfma_kernel(const short* __restrict__ G16,
                                                       const short* __restrict__ E16,
                                                       float* __restrict__ part, int nchunk) {
    int lane = threadIdx.x & 63;
    int wave = threadIdx.x >> 6;
    int quad = lane >> 4;
    int rr = lane & 15;
    int rowbase = blockIdx.x * 64 + wave * 16;
    const short8* ga = (const short8*)(G16 + (size_t)(rowbase + rr) * 64 + quad * 8);
    short8 a0 = ga[0];
    short8 a1 = ga[4];
    int c0 = blockIdx.y * CPC;
    float s0 = 0.f, s1 = 0.f, s2 = 0.f, s3 = 0.f;
    for (int ct = 0; ct < CPC; ct += 16) {
        const short8* eb = (const short8*)(E16 + (size_t)(c0 + ct + rr) * 64 + quad * 8);
        short8 b0 = eb[0];
        short8 b1 = eb[4];
        floatx4 acc = {0.f, 0.f, 0.f, 0.f};
        acc = __builtin_amdgcn_mfma_f32_16x16x32_bf16(a0, b0, acc, 0, 0, 0);
        acc = __builtin_amdgcn_mfma_f32_16x16x32_bf16(a1, b1, acc, 0, 0, 0);
        s0 += __expf(acc[0] * 5.f);
        s1 += __expf(acc[1] * 5.f);
        s2 += __expf(acc[2] * 5.f);
        s3 += __expf(acc[3] * 5.f);
    }
#pragma unroll
    for (int m = 8; m; m >>= 1) {
        s0 += __shfl_xor(s0, m);
        s1 += __shfl_xor(s1, m);
        s2 += __shfl_xor(s2, m);
        s3 += __shfl_xor(s3, m);
    }
    if (rr == 0) {
        int row = rowbase + quad * 4;
        float* p = part + (size_t)row * nchunk + blockIdx.y;
        p[0] = s0;
        p[(size_t)nchunk] = s1;
        p[(size_t)2 * nchunk] = s2;
        p[(size_t)3 * nchunk] = s3;
    }
}

__global__ void combine_kernel(const float* __restrict__ part, int m, int nchunk, float pad,
                               float* __restrict__ acc, float coef) {
    int row = blockIdx.x * blockDim.x + threadIdx.x;
    if (row >= m) return;
    float S = 0.f;
    for (int c = 0; c < nchunk; c++) S += part[row * nchunk + c];
    float lse = __logf(S - pad);
    atomicAdd(acc, coef * lse);
}

__global__ void cat_kernel(const float* __restrict__ img, const float* __restrict__ txt,
                           float* __restrict__ out, int nrows) {
    int lane = threadIdx.x & 63;
    int row = (blockIdx.x * blockDim.x + threadIdx.x) >> 6;
    if (row >= nrows) return;
    float a = img[row * 64 + lane], b = txt[row * 64 + lane];
    float sa = a * a, sb = b * b;
#pragma unroll
    for (int msk = 32; msk; msk >>= 1) { sa += __shfl_xor(sa, msk); sb += __shfl_xor(sb, msk); }
    float ia = 1.f / fmaxf(sqrtf(sa), 1e-12f);
    float ib = 1.f / fmaxf(sqrtf(sb), 1e-12f);
    out[row * 64 + lane] += 0.02f * (a * ia + b * ib);
}

__global__ void loss_write_kernel(const float* __restrict__ acc, float* __restrict__ out) {
    out[0] = acc[0];
}

extern "C" void kernel_launch(void* const* d_in, const int* in_sizes, int n_in,
                              void* d_out, int out_size, void* d_ws, size_t ws_size,
                              hipStream_t stream) {
    const float* user_emb = (const float*)d_in[0];
    const float* item_emb = (const float*)d_in[1];
    const float* user_pre = (const float*)d_in[2];
    const float* item_pre = (const float*)d_in[3];
    const float* img_i = (const float*)d_in[4];
    const float* txt_i = (const float*)d_in[5];
    const float* img_u = (const float*)d_in[6];
    const float* txt_u = (const float*)d_in[7];
    const int* rows = (const int*)d_in[8];
    const int* cols = (const int*)d_in[9];
    const float* vals = (const float*)d_in[10];
    const float* ut = (const float*)d_in[11];
    const float* vt = (const float*)d_in[12];
    const float* u_mul_s = (const float*)d_in[13];
    const float* v_mul_s = (const float*)d_in[14];
    const int* uids = (const int*)d_in[15];
    const int* iids = (const int*)d_in[16];

    float* ws = (float*)d_ws;
    float* zu1 = ws + ZU1;
    float* zi1 = ws + ZI1;
    float2* edge = (float2*)(ws + EDGE);
    float* P = ws + P_OFF;
    float* Q = ws + Q_OFF;
    float* acc = ws + ACC_OFF;
    int* cnt = (int*)(ws + CNT_OFF);
    int* off = (int*)(ws + OFF_OFF);
    int* bsum = (int*)(ws + BSUM_OFF);
    float* eu0 = ws + EU0;
    float* ei0 = ws + EI0;
    float* part_u = ws + PART_U;
    float* part_i = ws + PART_I;
    short* ebu16 = (short*)(ws + EBU16);
    short* ebi16 = (short*)(ws + EBI16);
    short* gbu16 = (short*)(ws + GBU16);
    short* gbi16 = (short*)(ws + GBI16);

    float* out_u = (float*)d_out;
    float* out_i = out_u + (size_t)N_U * 64;
    float* out_loss = out_u + (size_t)(N_U + N_I) * 64;

    const int NB = (NSEG + 255) / 256;  // 586 scan blocks

    // zero P,Q,acc,cnt (small)
    hipMemsetAsync(ws + P_OFF, 0, (ZERO_END - P_OFF) * sizeof(float), stream);

    // E0 = pre + emb
    ew_add_kernel<<<6250, 256, 0, stream>>>((const float4*)user_emb, (const float4*)user_pre,
                                            (float4*)eu0, 1600000);
    ew_add_kernel<<<3125, 256, 0, stream>>>((const float4*)item_emb, (const float4*)item_pre,
                                            (float4*)ei0, 800000);
    // build CSR/CSC (combined segment array: [0,N_U) rows, [N_U,NSEG) cols)
    hist_kernel<<<(NNZ_ + 255) / 256, 256, 0, stream>>>(rows, cols, cnt);
    scan1_kernel<<<NB, 256, 0, stream>>>(cnt, bsum, NSEG);
    scan2_kernel<<<1, 1024, 0, stream>>>(bsum, NB);
    scan3_kernel<<<NB, 256, 0, stream>>>(cnt, bsum, off, NSEG);
    scatter_kernel<<<(NNZ_ + 255) / 256, 256, 0, stream>>>(rows, cols, vals, off, edge);
    // layer-1 rank reductions
    rank_kernel<<<256, 256, 0, stream>>>(ei0, vt, P, N_I);
    rank_kernel<<<256, 256, 0, stream>>>(eu0, ut, Q, N_U);
    // layer-1 SpMM (CSR, no atomics)
    spmm_csr_kernel<<<N_U / 4, 256, 0, stream>>>(edge, off, cnt, 0, ei0, zu1, 1.f, 0, N_U);
    spmm_csr_kernel<<<N_I / 4, 256, 0, stream>>>(edge, off, cnt, N_U, eu0, zi1, 1.f, 0, N_I);
    // layer-2 rank reductions
    rank_kernel<<<256, 256, 0, stream>>>(zi1, vt, P, N_I);
    rank_kernel<<<256, 256, 0, stream>>>(zu1, ut, Q, N_U);
    // out = (E0 + Z1)/3, then layer-2 SpMM accumulates Z2/3 into out
    pre_out_kernel<<<6250, 256, 0, stream>>>((const float4*)eu0, (const float4*)zu1,
                                             (float4*)out_u, 1600000);
    pre_out_kernel<<<3125, 256, 0, stream>>>((const float4*)ei0, (const float4*)zi1,
                                             (float4*)out_i, 800000);
    spmm_csr_kernel<<<N_U / 4, 256, 0, stream>>>(edge, off, cnt, 0, zi1, out_u, 1.f / 3.f, 1,
                                                 N_U);
    spmm_csr_kernel<<<N_I / 4, 256, 0, stream>>>(edge, off, cnt, N_U, zu1, out_i, 1.f / 3.f, 1,
                                                 N_I);
    // bf16 copies of E (overlay in dead zu1 region; zero-padded tail rows)
    conv_bf16_kernel<<<(NPAD_U * 64 + 255) / 256, 256, 0, stream>>>(out_u, ebu16, N_U * 64,
                                                                   NPAD_U * 64);
    conv_bf16_kernel<<<(NPAD_I * 64 + 255) / 256, 256, 0, stream>>>(out_i, ebi16, N_I * 64,
                                                                   NPAD_I * 64);
    // sampled G rows (bf16) + pos term (fp32)
    gather_kernel<<<M_U / 4, 256, 0, stream>>>(uids, M_U, eu0, P, u_mul_s, out_u, gbu16, acc,
                                               -4.f / M_U);
    gather_kernel<<<M_I / 4, 256, 0, stream>>>(iids, M_I, ei0, Q, v_mul_s, out_i, gbi16, acc,
                                               -4.f / M_I);
    // neg term: MFMA exp-sum
    dim3 gu(M_U / 64, NCH_U);
    neg_mfma_kernel<<<gu, 256, 0, stream>>>(gbu16, ebu16, part_u, NCH_U);
    dim3 gi(M_I / 64, NCH_I);
    neg_mfma_kernel<<<gi, 256, 0, stream>>>(gbi16, ebi16, part_i, NCH_I);
    combine_kernel<<<(M_U + 255) / 256, 256, 0, stream>>>(part_u, M_U, NCH_U,
                                                          (float)(NPAD_U - N_U), acc, 4.f / M_U);
    combine_kernel<<<(M_I + 255) / 256, 256, 0, stream>>>(part_i, M_I, NCH_I,
                                                          (float)(NPAD_I - N_I), acc, 4.f / M_I);
    // cat-rate terms (after loss consumed E from d_out)
    cat_kernel<<<(N_U * 64 + 255) / 256, 256, 0, stream>>>(img_u, txt_u, out_u, N_U);
    cat_kernel<<<(N_I * 64 + 255) / 256, 256, 0, stream>>>(img_i, txt_i, out_i, N_I);
    loss_write_kernel<<<1, 1, 0, stream>>>(acc, out_loss);
}